// Round 22
// baseline (165.715 us; speedup 1.0000x reference)
//
#include <hip/hip_runtime.h>
#include <hip/hip_bf16.h>

// Problem constants
// B=128, C=512, H=W=14 -> HW=196, M=B*HW=25088, P=512
#define Bn   128
#define Cn   512
#define HWn  196
#define Mn   25088
#define Pn   512
#define SPLITK2 32         // GEMM2 split-K chunks of 1024 m'
#define KCH  1024
// fragment-tiled layouts (one wave fragment = 16 rows x 32 k = 1KB contiguous):
//   at/xt bf16: idx = (row>>4)*524288 + (m'>>5)*512 + (row&15)*32 + (m'&31)
//   wf   fp16: idx = (n>>4)*8192   + (k>>5)*512  + (n&15)*32  + (k&31)
// m' = b*256 + chunk*64 + j  (chunk = hw/49, j = hw%49; j>=49 zero pads)

// ws layout (float offsets)
#define OFF_XT     0u          // bf16 tiled [512][32768] = 8,388,608 f
#define OFF_AT     8388608u    // bf16 tiled [512][32768] = 8,388,608 f
#define OFF_PART   16777216u   // 32*512*512 bf16 = 4,194,304 f
#define OFF_WF     20971520u   // fp16 tiled [512][512] = 131,072 f
#define OFF_WNORM  21102592u   // 512
#define OFF_RAWP   21103104u   // 256*512 = 131,072
#define OFF_MEAN   21234176u   // 512
// total = 21,234,688 floats = 84.9 MB

// d_out layout (float offsets)
#define OUT_CAT  0u        // 128*1024
#define OUT_WSUM 131072u   // 512*512
#define OUT_WNUM 393216u   // 512

using bf16x8 = __attribute__((ext_vector_type(8))) short;
using f16x8  = __attribute__((ext_vector_type(8))) _Float16;
using f32x4  = __attribute__((ext_vector_type(4))) float;

__device__ __forceinline__ unsigned short f2b(float f) {
    union { float f; unsigned u; } x; x.f = f;
    unsigned r = x.u + 0x7fffu + ((x.u >> 16) & 1u);   // RNE
    return (unsigned short)(r >> 16);
}
__device__ __forceinline__ float b2f(unsigned short u) {
    union { unsigned u; float f; } x; x.u = ((unsigned)u) << 16;
    return x.f;
}

// ---------------- wnorm: ||w_n||^2  + w -> fp16 fragment-tiled ----------
__global__ __launch_bounds__(64) void k_wnorm(const float* __restrict__ w,
                                              float* __restrict__ wn,
                                              _Float16* __restrict__ wf) {
    int n = blockIdx.x, l = threadIdx.x;
    const float* p = w + (size_t)n * Cn + l * 8;
    float4 a = *(const float4*)p;
    float4 b = *(const float4*)(p + 4);
    float s = a.x*a.x + a.y*a.y + a.z*a.z + a.w*a.w
            + b.x*b.x + b.y*b.y + b.z*b.z + b.w*b.w;
    alignas(16) _Float16 h[8];
    h[0]=(_Float16)a.x; h[1]=(_Float16)a.y; h[2]=(_Float16)a.z; h[3]=(_Float16)a.w;
    h[4]=(_Float16)b.x; h[5]=(_Float16)b.y; h[6]=(_Float16)b.z; h[7]=(_Float16)b.w;
    *(float4*)(wf + (size_t)(n >> 4) * 8192u + (size_t)(l >> 2) * 512
                 + (n & 15) * 32 + (l & 3) * 8) = *(const float4*)h;
    #pragma unroll
    for (int o = 32; o > 0; o >>= 1) s += __shfl_down(s, o);
    if (l == 0) wn[n] = s;
}

// --- k_post: fused fm-stage + GEMM1(fp16 MFMA) + softmax + threshold
//             + at-write + xt-write + colsums  (prep kernel eliminated) ---
// grid 256: block = (b, half) -> 98 rows x all 512 n. 8 waves (2 mq x 4 nq).
// A staged ONCE from fm (fp32->fp16, coalesced along hw) into 117.5 KB LDS;
// 16 segs of pure {ds_read + contiguous wf loads + MFMA} -- no barriers.
// Epilogue additionally writes xt (bf16 frag-tiled, pads zeroed) from LDS.
__global__ __launch_bounds__(512) void k_post(const float* __restrict__ fm,
                                              const _Float16* __restrict__ wf,
                                              const float* __restrict__ wnorm,
                                              unsigned short* __restrict__ at,
                                              unsigned short* __restrict__ xt,
                                              float* __restrict__ rawp) {
    __shared__ _Float16 As[113][520];    // 1040B row stride == 4 banks mod 32
    __shared__ float red[2][64][4];
    __shared__ float colp[2][512];
    const int bid = blockIdx.x;
    const int b = bid >> 1, half = bid & 1;
    const int tid = threadIdx.x;
    const int wave = tid >> 6, lane = tid & 63;
    const int mq = wave >> 2, nq = wave & 3;
    const int rl = lane & 15, rq = lane >> 4;
    const int kb = rq * 8;
    const int m0 = b * 196 + half * 98;
    const int n0 = nq * 128;

    // ---- stage A from fm: rows 0..112 (clamped; rows 98..112 are masked
    // pads downstream), lanes along hw -> coalesced fp32 reads ----
    {
        const int cg = tid >> 6;           // wave id = c phase
        int m1 = m0 + lane;        if (m1 > Mn - 1) m1 = Mn - 1;
        int m2 = m0 + lane + 64;   if (m2 > Mn - 1) m2 = Mn - 1;
        const int b1 = m1 / HWn, h1 = m1 - b1 * HWn;
        const int b2 = m2 / HWn, h2 = m2 - b2 * HWn;
        const float* f1 = fm + (size_t)b1 * (Cn * HWn) + h1;
        const float* f2 = fm + (size_t)b2 * (Cn * HWn) + h2;
        const bool ok2 = (lane + 64) < 113;
        for (int c = cg; c < Cn; c += 8) {
            As[lane][c] = (_Float16)f1[(size_t)c * HWn];
            if (ok2) As[lane + 64][c] = (_Float16)f2[(size_t)c * HWn];
        }
    }
    __syncthreads();

    const _Float16* wtb = wf + (size_t)(nq * 8) * 8192u + rl * 32 + kb;

    f32x4 acc[4][8] = {};
    for (int seg = 0; seg < 16; ++seg) {
        f16x8 a[4], bb[8];
        #pragma unroll
        for (int f = 0; f < 4; ++f)
            a[f] = *(const f16x8*)&As[mq * 49 + f * 16 + rl][seg * 32 + kb];
        #pragma unroll
        for (int g = 0; g < 8; ++g)
            bb[g] = *(const f16x8*)(wtb + (size_t)g * 8192u + seg * 512);
        #pragma unroll
        for (int f = 0; f < 4; ++f)
            #pragma unroll
            for (int g = 0; g < 8; ++g)
                acc[f][g] = __builtin_amdgcn_mfma_f32_16x16x32_f16(a[f], bb[g], acc[f][g], 0, 0, 0);
    }
    // scores: 2*dot - ||w||^2
    float wn[8];
    #pragma unroll
    for (int g = 0; g < 8; ++g) wn[g] = wnorm[n0 + g * 16 + rl];
    #pragma unroll
    for (int f = 0; f < 4; ++f)
        #pragma unroll
        for (int g = 0; g < 8; ++g)
            #pragma unroll
            for (int r = 0; r < 4; ++r)
                acc[f][g][r] = 2.0f * acc[f][g][r] - wn[g];
    // row max across block
    float mx[4][4];
    #pragma unroll
    for (int f = 0; f < 4; ++f)
        #pragma unroll
        for (int r = 0; r < 4; ++r) {
            float m_ = acc[f][0][r];
            #pragma unroll
            for (int g = 1; g < 8; ++g) m_ = fmaxf(m_, acc[f][g][r]);
            #pragma unroll
            for (int o = 8; o >= 1; o >>= 1) m_ = fmaxf(m_, __shfl_xor(m_, o));
            mx[f][r] = m_;
        }
    if (rl == 0)
        #pragma unroll
        for (int f = 0; f < 4; ++f)
            #pragma unroll
            for (int r = 0; r < 4; ++r)
                red[mq][f * 16 + rq * 4 + r][nq] = mx[f][r];
    __syncthreads();
    float rmax[4][4];
    #pragma unroll
    for (int f = 0; f < 4; ++f)
        #pragma unroll
        for (int r = 0; r < 4; ++r) {
            float* q = red[mq][f * 16 + rq * 4 + r];
            rmax[f][r] = fmaxf(fmaxf(q[0], q[1]), fmaxf(q[2], q[3]));
        }
    // exp + row sums
    float sm[4][4];
    #pragma unroll
    for (int f = 0; f < 4; ++f)
        #pragma unroll
        for (int r = 0; r < 4; ++r) {
            float s_ = 0.f;
            #pragma unroll
            for (int g = 0; g < 8; ++g) {
                float p = __expf(acc[f][g][r] - rmax[f][r]);
                acc[f][g][r] = p;
                s_ += p;
            }
            #pragma unroll
            for (int o = 8; o >= 1; o >>= 1) s_ += __shfl_xor(s_, o);
            sm[f][r] = s_;
        }
    __syncthreads();
    if (rl == 0)
        #pragma unroll
        for (int f = 0; f < 4; ++f)
            #pragma unroll
            for (int r = 0; r < 4; ++r)
                red[mq][f * 16 + rq * 4 + r][nq] = sm[f][r];
    __syncthreads();
    const float invP = 1.0f / 512.0f;
    #pragma unroll
    for (int f = 0; f < 4; ++f)
        #pragma unroll
        for (int r = 0; r < 4; ++r) {
            float* q = red[mq][f * 16 + rq * 4 + r];
            float inv = 1.0f / (q[0] + q[1] + q[2] + q[3]);
            #pragma unroll
            for (int g = 0; g < 8; ++g) {
                float a = acc[f][g][r] * inv;
                acc[f][g][r] = (a < invP) ? 0.0f : a;
            }
        }
    // column sums over valid rows (mloc < 49)
    float cs[8] = {};
    #pragma unroll
    for (int g = 0; g < 8; ++g) {
        #pragma unroll
        for (int f = 0; f < 4; ++f)
            #pragma unroll
            for (int r = 0; r < 4; ++r)
                if (f * 16 + rq * 4 + r < 49) cs[g] += acc[f][g][r];
        cs[g] += __shfl_xor(cs[g], 16);
        cs[g] += __shfl_xor(cs[g], 32);
    }
    if (rq == 0)
        #pragma unroll
        for (int g = 0; g < 8; ++g) colp[mq][n0 + g * 16 + rl] = cs[g];
    __syncthreads();
    if (tid < 512) rawp[(size_t)bid * 512 + tid] = colp[0][tid] + colp[1][tid];
    // at write (tiled layout): rows n0+g*16+rl, m' = mb + mloc
    const int mb = b * 256 + (half * 2 + mq) * 64;
    const int segbase = mb >> 5;
    #pragma unroll
    for (int f = 0; f < 4; ++f) {
        const int mloc = f * 16 + rq * 4;
        const int seg = segbase + (mloc >> 5);
        const int k = mloc & 31;
        #pragma unroll
        for (int g = 0; g < 8; ++g) {
            ushort4 o;
            o.x = (mloc + 0 < 49) ? f2b(acc[f][g][0]) : (unsigned short)0;
            o.y = (mloc + 1 < 49) ? f2b(acc[f][g][1]) : (unsigned short)0;
            o.z = (mloc + 2 < 49) ? f2b(acc[f][g][2]) : (unsigned short)0;
            o.w = (mloc + 3 < 49) ? f2b(acc[f][g][3]) : (unsigned short)0;
            const int T = nq * 8 + g;
            *(ushort4*)(at + (size_t)T * 524288u + (size_t)seg * 512 + rl * 32 + k) = o;
        }
    }
    // xt write from As (fp16 -> bf16, pads zero): this block's 2 m'-chunks
    for (int i = tid; i < 512 * 32; i += 512) {
        const int c = i >> 5;
        const int g4 = (i & 31) << 2;     // 0..124 step 4
        const int ch = g4 >> 6;           // chunk 0/1 within this half
        const int mloc = g4 & 63;
        const int lr = ch * 49 + mloc;    // LDS row
        ushort4 o;
        if (mloc < 48) {
            o.x = f2b((float)As[lr][c]);
            o.y = f2b((float)As[lr + 1][c]);
            o.z = f2b((float)As[lr + 2][c]);
            o.w = f2b((float)As[lr + 3][c]);
        } else if (mloc == 48) {
            o.x = f2b((float)As[lr][c]); o.y = 0; o.z = 0; o.w = 0;
        } else {
            o.x = 0; o.y = 0; o.z = 0; o.w = 0;
        }
        const int seg = b * 8 + (half * 2 + ch) * 2 + (mloc >> 5);
        *(ushort4*)(xt + (size_t)(c >> 4) * 524288u + (size_t)seg * 512
                    + (c & 15) * 32 + (mloc & 31)) = o;
    }
}

// ---------------- assign_mean + new_w_ep_num ----------------
__global__ __launch_bounds__(256) void k_reduce(const float* __restrict__ rawp,
                                                const float* __restrict__ wnum,
                                                float* __restrict__ mean,
                                                float* __restrict__ outnum) {
    int n = blockIdx.x * 256 + threadIdx.x;
    float s = 0.f;
    for (int r = 0; r < 256; ++r) s += rawp[(size_t)r * Pn + n];
    mean[n] = s;
    outnum[n] = wnum[n] + (s > 1.0f ? s : 0.0f);
}

// ---------------- cvec + concat ----------------
__global__ __launch_bounds__(256) void k_cvec(const float* __restrict__ rawp,
                                              const float* __restrict__ w,
                                              const float* __restrict__ emb,
                                              const int* __restrict__ epoch,
                                              float* __restrict__ out) {
    __shared__ float srow[512];
    int b = blockIdx.x, t = threadIdx.x;
    srow[t]       = rawp[(size_t)(2*b) * Pn + t]       + rawp[(size_t)(2*b+1) * Pn + t];
    srow[t + 256] = rawp[(size_t)(2*b) * Pn + t + 256] + rawp[(size_t)(2*b+1) * Pn + t + 256];
    __syncthreads();
    float a0 = 0.f, a1 = 0.f;
    for (int p = 0; p < Pn; ++p) {
        float ap = srow[p];
        a0 = fmaf(ap, w[(size_t)p * Cn + t], a0);
        a1 = fmaf(ap, w[(size_t)p * Cn + t + 256], a1);
    }
    const float sc = 1.0f / (196.0f * 512.0f);
    int ep = epoch[0];
    float c0 = (ep > 2) ? fmaxf(a0, 0.f) * sc : 0.f;
    float c1 = (ep > 2) ? fmaxf(a1, 0.f) * sc : 0.f;
    out[(size_t)b * 1024 + t]             = emb[(size_t)b * Cn + t];
    out[(size_t)b * 1024 + t + 256]       = emb[(size_t)b * Cn + t + 256];
    out[(size_t)b * 1024 + 512 + t]       = c0;
    out[(size_t)b * 1024 + 512 + t + 256] = c1;
}

// ---------------- GEMM2 (MFMA, fragment-tiled direct-global, reg dbuf): --
// update_w[n][c] = sum_m' at[n][m']*xt[c][m']  -- bf16 partials
// grid 512 = 16 tiles (4n x 4c of 128x128) x 32 K-chunks, z-major for XCD.
__global__ __launch_bounds__(256) void k_upw_mfma(const unsigned short* __restrict__ at,
                                                  const unsigned short* __restrict__ xt,
                                                  unsigned short* __restrict__ part) {
    const int id = blockIdx.x;
    const int sp = id & 31;        // K-chunk
    const int m  = id >> 5;        // 0..15
    const int tid = threadIdx.x;
    const int wave = tid >> 6, lane = tid & 63;
    const int wn = wave >> 1, wc = wave & 1;
    const int n0 = (m & 3) * 128;
    const int c0 = (m >> 2) * 128;
    const int rl = lane & 15, rq = lane >> 4;
    const int loff = rl * 32 + rq * 8;       // lane offset within 512-elem frag
    const int segbase = sp * 32;             // seg = sp*32 + ks

    const unsigned short* pa[4];
    const unsigned short* pb[4];
    #pragma unroll
    for (int f = 0; f < 4; ++f) {
        const int Ta = (n0 >> 4) + wn * 4 + f;
        const int Tb = (c0 >> 4) + wc * 4 + f;
        pa[f] = at + (size_t)Ta * 524288u + (size_t)segbase * 512 + loff;
        pb[f] = xt + (size_t)Tb * 524288u + (size_t)segbase * 512 + loff;
    }

    f32x4 acc[4][4] = {};
    bf16x8 aC[4], bC[4], aN[4], bN[4];
    #pragma unroll
    for (int f = 0; f < 4; ++f) {
        aC[f] = *(const bf16x8*)(pa[f]);
        bC[f] = *(const bf16x8*)(pb[f]);
    }
    for (int ks = 0; ks < 32; ks += 2) {
        #pragma unroll
        for (int f = 0; f < 4; ++f) {
            aN[f] = *(const bf16x8*)(pa[f] + (ks + 1) * 512);
            bN[f] = *(const bf16x8*)(pb[f] + (ks + 1) * 512);
        }
        #pragma unroll
        for (int i = 0; i < 4; ++i)
            #pragma unroll
            for (int j = 0; j < 4; ++j)
                acc[i][j] = __builtin_amdgcn_mfma_f32_16x16x32_bf16(aC[i], bC[j], acc[i][j], 0, 0, 0);
        if (ks + 2 < 32) {
            #pragma unroll
            for (int f = 0; f < 4; ++f) {
                aC[f] = *(const bf16x8*)(pa[f] + (ks + 2) * 512);
                bC[f] = *(const bf16x8*)(pb[f] + (ks + 2) * 512);
            }
        }
        #pragma unroll
        for (int i = 0; i < 4; ++i)
            #pragma unroll
            for (int j = 0; j < 4; ++j)
                acc[i][j] = __builtin_amdgcn_mfma_f32_16x16x32_bf16(aN[i], bN[j], acc[i][j], 0, 0, 0);
    }
    unsigned short* o = part + (size_t)sp * (Pn * Cn);
    const int rq4 = rq * 4;
    #pragma unroll
    for (int i = 0; i < 4; ++i) {
        #pragma unroll
        for (int j = 0; j < 4; ++j) {
            int n = n0 + wn * 64 + i * 16 + rq4;
            int c = c0 + wc * 64 + j * 16 + rl;
            #pragma unroll
            for (int r = 0; r < 4; ++r)
                o[(size_t)(n + r) * Cn + c] = f2b(acc[i][j][r]);
        }
    }
}

// ---------------- epilogue: new_w_ep_sum (bf16 partials, ushort2 loads) --
__global__ __launch_bounds__(256) void k_wep(const unsigned short* __restrict__ part,
                                             const float* __restrict__ mean,
                                             const float* __restrict__ wsum,
                                             float* __restrict__ out1) {
    int n = blockIdx.x, t = threadIdx.x;
    bool upd = mean[n] > 1.0f;
    int c = t * 2;
    float s0 = 0.f, s1 = 0.f;
    #pragma unroll
    for (int k = 0; k < SPLITK2; ++k) {
        ushort2 v = *(const ushort2*)(part + (size_t)k * (Pn * Cn) + (size_t)n * Cn + c);
        s0 += b2f(v.x);
        s1 += b2f(v.y);
    }
    size_t idx = (size_t)n * Cn + c;
    out1[idx]     = wsum[idx]     + (upd ? s0 : 0.f);
    out1[idx + 1] = wsum[idx + 1] + (upd ? s1 : 0.f);
}

extern "C" void kernel_launch(void* const* d_in, const int* in_sizes, int n_in,
                              void* d_out, int out_size, void* d_ws, size_t ws_size,
                              hipStream_t stream) {
    const float* fm    = (const float*)d_in[0];
    const float* emb   = (const float*)d_in[1];
    const float* w     = (const float*)d_in[2];
    const float* wsum  = (const float*)d_in[3];
    const float* wnum  = (const float*)d_in[4];
    const int*   epoch = (const int*)d_in[5];
    float* out = (float*)d_out;
    float* wsf = (float*)d_ws;

    unsigned short* xtb   = (unsigned short*)(wsf + OFF_XT);
    unsigned short* atb   = (unsigned short*)(wsf + OFF_AT);
    unsigned short* partb = (unsigned short*)(wsf + OFF_PART);
    _Float16*       wfb   = (_Float16*)(wsf + OFF_WF);
    float*          wnormb = wsf + OFF_WNORM;
    float*          rawpb  = wsf + OFF_RAWP;
    float*          meanb  = wsf + OFF_MEAN;

    k_wnorm<<<512, 64, 0, stream>>>(w, wnormb, wfb);
    k_post<<<256, 512, 0, stream>>>(fm, wfb, wnormb, atb, xtb, rawpb);
    k_reduce<<<2, 256, 0, stream>>>(rawpb, wnum, meanb, out + OUT_WNUM);
    k_cvec<<<Bn, 256, 0, stream>>>(rawpb, w, emb, epoch, out + OUT_CAT);
    k_upw_mfma<<<512, 256, 0, stream>>>(atb, xtb, partb);
    k_wep<<<Pn, 256, 0, stream>>>(partb, meanb, wsum, out + OUT_WSUM);
}

// Round 23
// 147.913 us; speedup vs baseline: 1.1204x; 1.1204x over previous
//
#include <hip/hip_runtime.h>
#include <hip/hip_bf16.h>

// Problem constants
// B=128, C=512, H=W=14 -> HW=196, M=B*HW=25088, P=512
#define Bn   128
#define Cn   512
#define HWn  196
#define Mn   25088
#define Pn   512
#define SPLITK2 32         // GEMM2 split-K chunks of 1024 m'
#define KCH  1024
// fragment-tiled layouts (one wave fragment = 16 rows x 32 k = 1KB contiguous):
//   at/xt bf16: idx = (row>>4)*524288 + (m'>>5)*512 + (row&15)*32 + (m'&31)
//   wf   fp16: idx = (n>>4)*8192   + (k>>5)*512  + (n&15)*32  + (k&31)

// ws layout (float offsets) -- round-12/17 proven
#define OFF_XT     0u          // bf16 tiled [512][32768] = 8,388,608 f
#define OFF_AT     8388608u    // bf16 tiled [512][32768] = 8,388,608 f
#define OFF_PART   16777216u   // 32*512*512 bf16 = 4,194,304 f (region kept 8,388,608 f for XM alias)
#define OFF_XM     16777216u   // fp16 [M][C] = 6,422,528 f (alias PART: xm dead before GEMM2)
#define OFF_WF     25165824u   // fp16 tiled [512][512] = 131,072 f
#define OFF_WNORM  25296896u   // 512
#define OFF_RAWP   25297408u   // 256*512 = 131,072
#define OFF_MEAN   25428480u   // 512
// total = 25,428,992 floats = 101.7 MB

// d_out layout (float offsets)
#define OUT_CAT  0u        // 128*1024
#define OUT_WSUM 131072u   // 512*512
#define OUT_WNUM 393216u   // 512

using bf16x8 = __attribute__((ext_vector_type(8))) short;
using f16x8  = __attribute__((ext_vector_type(8))) _Float16;
using f32x4  = __attribute__((ext_vector_type(4))) float;

__device__ __forceinline__ unsigned short f2b(float f) {
    union { float f; unsigned u; } x; x.f = f;
    unsigned r = x.u + 0x7fffu + ((x.u >> 16) & 1u);   // RNE
    return (unsigned short)(r >> 16);
}
__device__ __forceinline__ float b2f(unsigned short u) {
    union { unsigned u; float f; } x; x.u = ((unsigned)u) << 16;
    return x.f;
}

// ---------------- wnorm: ||w_n||^2  + w -> fp16 fragment-tiled ----------
__global__ __launch_bounds__(64) void k_wnorm(const float* __restrict__ w,
                                              float* __restrict__ wn,
                                              _Float16* __restrict__ wf) {
    int n = blockIdx.x, l = threadIdx.x;
    const float* p = w + (size_t)n * Cn + l * 8;
    float4 a = *(const float4*)p;
    float4 b = *(const float4*)(p + 4);
    float s = a.x*a.x + a.y*a.y + a.z*a.z + a.w*a.w
            + b.x*b.x + b.y*b.y + b.z*b.z + b.w*b.w;
    alignas(16) _Float16 h[8];
    h[0]=(_Float16)a.x; h[1]=(_Float16)a.y; h[2]=(_Float16)a.z; h[3]=(_Float16)a.w;
    h[4]=(_Float16)b.x; h[5]=(_Float16)b.y; h[6]=(_Float16)b.z; h[7]=(_Float16)b.w;
    *(float4*)(wf + (size_t)(n >> 4) * 8192u + (size_t)(l >> 2) * 512
                 + (n & 15) * 32 + (l & 3) * 8) = *(const float4*)h;
    #pragma unroll
    for (int o = 32; o > 0; o >>= 1) s += __shfl_down(s, o);
    if (l == 0) wn[n] = s;
}

// ------- prep2: fm fp32 [b][c][hw] -> xm fp16 [m][c]  AND xt bf16 tiled ---
__global__ __launch_bounds__(512) void k_prep2(const float* __restrict__ fm,
                                               _Float16* __restrict__ xm,
                                               unsigned short* __restrict__ xt) {
    __shared__ _Float16 tile[64][200];
    int b = blockIdx.x;
    int cg = blockIdx.y * 64;
    int t = threadIdx.x;
    for (int i = t; i < 64 * 49; i += 512) {
        int cl = i / 49, h4 = i - cl * 49;
        float4 v = *(const float4*)(fm + ((size_t)(b * Cn + cg + cl) * HWn) + h4 * 4);
        tile[cl][h4*4+0] = (_Float16)v.x;
        tile[cl][h4*4+1] = (_Float16)v.y;
        tile[cl][h4*4+2] = (_Float16)v.z;
        tile[cl][h4*4+3] = (_Float16)v.w;
    }
    __syncthreads();
    // xm: transposed fp16 [m][c]
    for (int i = t; i < HWn * 8; i += 512) {
        int hw = i >> 3, seg = i & 7;
        alignas(16) _Float16 h[8];
        #pragma unroll
        for (int j = 0; j < 8; ++j) h[j] = tile[seg * 8 + j][hw];
        *(float4*)(xm + (size_t)(b * HWn + hw) * Cn + cg + seg * 8) = *(const float4*)h;
    }
    // xt tiled: c row, m' = b*256 + q*64 + j (j<49 valid, 49..63 zero)
    for (int i = t; i < 64 * 4 * 16; i += 512) {
        int cl = i >> 6, rem = i & 63;
        int q = rem >> 4, j4 = rem & 15;
        ushort4 o;
        if (j4 < 12) {
            o.x = f2b((float)tile[cl][q*49 + j4*4 + 0]);
            o.y = f2b((float)tile[cl][q*49 + j4*4 + 1]);
            o.z = f2b((float)tile[cl][q*49 + j4*4 + 2]);
            o.w = f2b((float)tile[cl][q*49 + j4*4 + 3]);
        } else if (j4 == 12) {
            o.x = f2b((float)tile[cl][q*49 + 48]);
            o.y = 0; o.z = 0; o.w = 0;
        } else {
            o.x = 0; o.y = 0; o.z = 0; o.w = 0;
        }
        int c = cg + cl;
        int T = c >> 4;
        int seg = b * 8 + q * 2 + (j4 >> 3);   // (m')>>5
        int k = (j4 & 7) * 4;                  // (m')&31
        *(ushort4*)(xt + (size_t)T * 524288u + (size_t)seg * 512 + (c & 15) * 32 + k) = o;
    }
}

// --- k_post: fused GEMM1(fp16 MFMA) + softmax + threshold + at + colsums --
// grid 256: block = (b, half) -> 98 rows x all 512 n. 8 waves (2 mq x 4 nq).
// A staged ONCE into 117.5 KB LDS (one barrier), then 16 segs of pure
// {ds_read + contiguous wf loads + MFMA} -- no barriers in the K loop.
__global__ __launch_bounds__(512) void k_post(const _Float16* __restrict__ xm,
                                              const _Float16* __restrict__ wf,
                                              const float* __restrict__ wnorm,
                                              unsigned short* __restrict__ at,
                                              float* __restrict__ rawp) {
    __shared__ _Float16 As[113][520];    // 1040B row stride == 4 banks mod 32
    __shared__ float red[2][64][4];
    __shared__ float colp[2][512];
    const int bid = blockIdx.x;
    const int b = bid >> 1, half = bid & 1;
    const int tid = threadIdx.x;
    const int wave = tid >> 6, lane = tid & 63;
    const int mq = wave >> 2, nq = wave & 3;
    const int rl = lane & 15, rq = lane >> 4;
    const int kb = rq * 8;
    const int m0 = b * 196 + half * 98;
    const int n0 = nq * 128;

    for (int i = tid; i < 113 * 64; i += 512) {
        int row = i >> 6, kc = (i & 63) * 8;
        *(f16x8*)&As[row][kc] = *(const f16x8*)(xm + (size_t)(m0 + row) * Cn + kc);
    }
    __syncthreads();

    const _Float16* wtb = wf + (size_t)(nq * 8) * 8192u + rl * 32 + kb;

    f32x4 acc[4][8] = {};
    for (int seg = 0; seg < 16; ++seg) {
        f16x8 a[4], bb[8];
        #pragma unroll
        for (int f = 0; f < 4; ++f)
            a[f] = *(const f16x8*)&As[mq * 49 + f * 16 + rl][seg * 32 + kb];
        #pragma unroll
        for (int g = 0; g < 8; ++g)
            bb[g] = *(const f16x8*)(wtb + (size_t)g * 8192u + seg * 512);
        #pragma unroll
        for (int f = 0; f < 4; ++f)
            #pragma unroll
            for (int g = 0; g < 8; ++g)
                acc[f][g] = __builtin_amdgcn_mfma_f32_16x16x32_f16(a[f], bb[g], acc[f][g], 0, 0, 0);
    }
    // scores: 2*dot - ||w||^2
    float wn[8];
    #pragma unroll
    for (int g = 0; g < 8; ++g) wn[g] = wnorm[n0 + g * 16 + rl];
    #pragma unroll
    for (int f = 0; f < 4; ++f)
        #pragma unroll
        for (int g = 0; g < 8; ++g)
            #pragma unroll
            for (int r = 0; r < 4; ++r)
                acc[f][g][r] = 2.0f * acc[f][g][r] - wn[g];
    // row max across block
    float mx[4][4];
    #pragma unroll
    for (int f = 0; f < 4; ++f)
        #pragma unroll
        for (int r = 0; r < 4; ++r) {
            float m_ = acc[f][0][r];
            #pragma unroll
            for (int g = 1; g < 8; ++g) m_ = fmaxf(m_, acc[f][g][r]);
            #pragma unroll
            for (int o = 8; o >= 1; o >>= 1) m_ = fmaxf(m_, __shfl_xor(m_, o));
            mx[f][r] = m_;
        }
    if (rl == 0)
        #pragma unroll
        for (int f = 0; f < 4; ++f)
            #pragma unroll
            for (int r = 0; r < 4; ++r)
                red[mq][f * 16 + rq * 4 + r][nq] = mx[f][r];
    __syncthreads();
    float rmax[4][4];
    #pragma unroll
    for (int f = 0; f < 4; ++f)
        #pragma unroll
        for (int r = 0; r < 4; ++r) {
            float* q = red[mq][f * 16 + rq * 4 + r];
            rmax[f][r] = fmaxf(fmaxf(q[0], q[1]), fmaxf(q[2], q[3]));
        }
    // exp + row sums
    float sm[4][4];
    #pragma unroll
    for (int f = 0; f < 4; ++f)
        #pragma unroll
        for (int r = 0; r < 4; ++r) {
            float s_ = 0.f;
            #pragma unroll
            for (int g = 0; g < 8; ++g) {
                float p = __expf(acc[f][g][r] - rmax[f][r]);
                acc[f][g][r] = p;
                s_ += p;
            }
            #pragma unroll
            for (int o = 8; o >= 1; o >>= 1) s_ += __shfl_xor(s_, o);
            sm[f][r] = s_;
        }
    __syncthreads();
    if (rl == 0)
        #pragma unroll
        for (int f = 0; f < 4; ++f)
            #pragma unroll
            for (int r = 0; r < 4; ++r)
                red[mq][f * 16 + rq * 4 + r][nq] = sm[f][r];
    __syncthreads();
    const float invP = 1.0f / 512.0f;
    #pragma unroll
    for (int f = 0; f < 4; ++f)
        #pragma unroll
        for (int r = 0; r < 4; ++r) {
            float* q = red[mq][f * 16 + rq * 4 + r];
            float inv = 1.0f / (q[0] + q[1] + q[2] + q[3]);
            #pragma unroll
            for (int g = 0; g < 8; ++g) {
                float a = acc[f][g][r] * inv;
                acc[f][g][r] = (a < invP) ? 0.0f : a;
            }
        }
    // column sums over valid rows (mloc < 49)
    float cs[8] = {};
    #pragma unroll
    for (int g = 0; g < 8; ++g) {
        #pragma unroll
        for (int f = 0; f < 4; ++f)
            #pragma unroll
            for (int r = 0; r < 4; ++r)
                if (f * 16 + rq * 4 + r < 49) cs[g] += acc[f][g][r];
        cs[g] += __shfl_xor(cs[g], 16);
        cs[g] += __shfl_xor(cs[g], 32);
    }
    if (rq == 0)
        #pragma unroll
        for (int g = 0; g < 8; ++g) colp[mq][n0 + g * 16 + rl] = cs[g];
    __syncthreads();
    if (tid < 512) rawp[(size_t)bid * 512 + tid] = colp[0][tid] + colp[1][tid];
    // at write (tiled layout): rows n0+g*16+rl, m' = mb + mloc
    const int mb = b * 256 + (half * 2 + mq) * 64;
    const int segbase = mb >> 5;
    #pragma unroll
    for (int f = 0; f < 4; ++f) {
        const int mloc = f * 16 + rq * 4;
        const int seg = segbase + (mloc >> 5);
        const int k = mloc & 31;
        #pragma unroll
        for (int g = 0; g < 8; ++g) {
            ushort4 o;
            o.x = (mloc + 0 < 49) ? f2b(acc[f][g][0]) : (unsigned short)0;
            o.y = (mloc + 1 < 49) ? f2b(acc[f][g][1]) : (unsigned short)0;
            o.z = (mloc + 2 < 49) ? f2b(acc[f][g][2]) : (unsigned short)0;
            o.w = (mloc + 3 < 49) ? f2b(acc[f][g][3]) : (unsigned short)0;
            const int T = nq * 8 + g;
            *(ushort4*)(at + (size_t)T * 524288u + (size_t)seg * 512 + rl * 32 + k) = o;
        }
    }
}

// ---------------- assign_mean + new_w_ep_num ----------------
__global__ __launch_bounds__(256) void k_reduce(const float* __restrict__ rawp,
                                                const float* __restrict__ wnum,
                                                float* __restrict__ mean,
                                                float* __restrict__ outnum) {
    int n = blockIdx.x * 256 + threadIdx.x;
    float s = 0.f;
    for (int r = 0; r < 256; ++r) s += rawp[(size_t)r * Pn + n];
    mean[n] = s;
    outnum[n] = wnum[n] + (s > 1.0f ? s : 0.0f);
}

// ---------------- cvec + concat ----------------
__global__ __launch_bounds__(256) void k_cvec(const float* __restrict__ rawp,
                                              const float* __restrict__ w,
                                              const float* __restrict__ emb,
                                              const int* __restrict__ epoch,
                                              float* __restrict__ out) {
    __shared__ float srow[512];
    int b = blockIdx.x, t = threadIdx.x;
    srow[t]       = rawp[(size_t)(2*b) * Pn + t]       + rawp[(size_t)(2*b+1) * Pn + t];
    srow[t + 256] = rawp[(size_t)(2*b) * Pn + t + 256] + rawp[(size_t)(2*b+1) * Pn + t + 256];
    __syncthreads();
    float a0 = 0.f, a1 = 0.f;
    for (int p = 0; p < Pn; ++p) {
        float ap = srow[p];
        a0 = fmaf(ap, w[(size_t)p * Cn + t], a0);
        a1 = fmaf(ap, w[(size_t)p * Cn + t + 256], a1);
    }
    const float sc = 1.0f / (196.0f * 512.0f);
    int ep = epoch[0];
    float c0 = (ep > 2) ? fmaxf(a0, 0.f) * sc : 0.f;
    float c1 = (ep > 2) ? fmaxf(a1, 0.f) * sc : 0.f;
    out[(size_t)b * 1024 + t]             = emb[(size_t)b * Cn + t];
    out[(size_t)b * 1024 + t + 256]       = emb[(size_t)b * Cn + t + 256];
    out[(size_t)b * 1024 + 512 + t]       = c0;
    out[(size_t)b * 1024 + 512 + t + 256] = c1;
}

// ---------------- GEMM2 (MFMA, fragment-tiled direct-global, reg dbuf): --
// update_w[n][c] = sum_m' at[n][m']*xt[c][m']  -- bf16 partials
// grid 512 = 16 tiles (4n x 4c of 128x128) x 32 K-chunks, z-major for XCD.
__global__ __launch_bounds__(256) void k_upw_mfma(const unsigned short* __restrict__ at,
                                                  const unsigned short* __restrict__ xt,
                                                  unsigned short* __restrict__ part) {
    const int id = blockIdx.x;
    const int sp = id & 31;        // K-chunk
    const int m  = id >> 5;        // 0..15
    const int tid = threadIdx.x;
    const int wave = tid >> 6, lane = tid & 63;
    const int wn = wave >> 1, wc = wave & 1;
    const int n0 = (m & 3) * 128;
    const int c0 = (m >> 2) * 128;
    const int rl = lane & 15, rq = lane >> 4;
    const int loff = rl * 32 + rq * 8;       // lane offset within 512-elem frag
    const int segbase = sp * 32;             // seg = sp*32 + ks

    const unsigned short* pa[4];
    const unsigned short* pb[4];
    #pragma unroll
    for (int f = 0; f < 4; ++f) {
        const int Ta = (n0 >> 4) + wn * 4 + f;
        const int Tb = (c0 >> 4) + wc * 4 + f;
        pa[f] = at + (size_t)Ta * 524288u + (size_t)segbase * 512 + loff;
        pb[f] = xt + (size_t)Tb * 524288u + (size_t)segbase * 512 + loff;
    }

    f32x4 acc[4][4] = {};
    bf16x8 aC[4], bC[4], aN[4], bN[4];
    #pragma unroll
    for (int f = 0; f < 4; ++f) {
        aC[f] = *(const bf16x8*)(pa[f]);
        bC[f] = *(const bf16x8*)(pb[f]);
    }
    for (int ks = 0; ks < 32; ks += 2) {
        #pragma unroll
        for (int f = 0; f < 4; ++f) {
            aN[f] = *(const bf16x8*)(pa[f] + (ks + 1) * 512);
            bN[f] = *(const bf16x8*)(pb[f] + (ks + 1) * 512);
        }
        #pragma unroll
        for (int i = 0; i < 4; ++i)
            #pragma unroll
            for (int j = 0; j < 4; ++j)
                acc[i][j] = __builtin_amdgcn_mfma_f32_16x16x32_bf16(aC[i], bC[j], acc[i][j], 0, 0, 0);
        if (ks + 2 < 32) {
            #pragma unroll
            for (int f = 0; f < 4; ++f) {
                aC[f] = *(const bf16x8*)(pa[f] + (ks + 2) * 512);
                bC[f] = *(const bf16x8*)(pb[f] + (ks + 2) * 512);
            }
        }
        #pragma unroll
        for (int i = 0; i < 4; ++i)
            #pragma unroll
            for (int j = 0; j < 4; ++j)
                acc[i][j] = __builtin_amdgcn_mfma_f32_16x16x32_bf16(aN[i], bN[j], acc[i][j], 0, 0, 0);
    }
    unsigned short* o = part + (size_t)sp * (Pn * Cn);
    const int rq4 = rq * 4;
    #pragma unroll
    for (int i = 0; i < 4; ++i) {
        #pragma unroll
        for (int j = 0; j < 4; ++j) {
            int n = n0 + wn * 64 + i * 16 + rq4;
            int c = c0 + wc * 64 + j * 16 + rl;
            #pragma unroll
            for (int r = 0; r < 4; ++r)
                o[(size_t)(n + r) * Cn + c] = f2b(acc[i][j][r]);
        }
    }
}

// ---------------- epilogue: new_w_ep_sum (bf16 partials, ushort2 loads) --
__global__ __launch_bounds__(256) void k_wep(const unsigned short* __restrict__ part,
                                             const float* __restrict__ mean,
                                             const float* __restrict__ wsum,
                                             float* __restrict__ out1) {
    int n = blockIdx.x, t = threadIdx.x;
    bool upd = mean[n] > 1.0f;
    int c = t * 2;
    float s0 = 0.f, s1 = 0.f;
    #pragma unroll
    for (int k = 0; k < SPLITK2; ++k) {
        ushort2 v = *(const ushort2*)(part + (size_t)k * (Pn * Cn) + (size_t)n * Cn + c);
        s0 += b2f(v.x);
        s1 += b2f(v.y);
    }
    size_t idx = (size_t)n * Cn + c;
    out1[idx]     = wsum[idx]     + (upd ? s0 : 0.f);
    out1[idx + 1] = wsum[idx + 1] + (upd ? s1 : 0.f);
}

extern "C" void kernel_launch(void* const* d_in, const int* in_sizes, int n_in,
                              void* d_out, int out_size, void* d_ws, size_t ws_size,
                              hipStream_t stream) {
    const float* fm    = (const float*)d_in[0];
    const float* emb   = (const float*)d_in[1];
    const float* w     = (const float*)d_in[2];
    const float* wsum  = (const float*)d_in[3];
    const float* wnum  = (const float*)d_in[4];
    const int*   epoch = (const int*)d_in[5];
    float* out = (float*)d_out;
    float* wsf = (float*)d_ws;

    unsigned short* xtb   = (unsigned short*)(wsf + OFF_XT);
    unsigned short* atb   = (unsigned short*)(wsf + OFF_AT);
    unsigned short* partb = (unsigned short*)(wsf + OFF_PART);
    _Float16*       xmb   = (_Float16*)(wsf + OFF_XM);   // alias of part (xm dead before GEMM2)
    _Float16*       wfb   = (_Float16*)(wsf + OFF_WF);
    float*          wnormb = wsf + OFF_WNORM;
    float*          rawpb  = wsf + OFF_RAWP;
    float*          meanb  = wsf + OFF_MEAN;

    k_wnorm<<<512, 64, 0, stream>>>(w, wnormb, wfb);
    k_prep2<<<dim3(Bn, 8), 512, 0, stream>>>(fm, xmb, xtb);
    k_post<<<256, 512, 0, stream>>>(xmb, wfb, wnormb, atb, rawpb);
    k_reduce<<<2, 256, 0, stream>>>(rawpb, wnum, meanb, out + OUT_WNUM);
    k_cvec<<<Bn, 256, 0, stream>>>(rawpb, w, emb, epoch, out + OUT_CAT);
    k_upw_mfma<<<512, 256, 0, stream>>>(atb, xtb, partb);
    k_wep<<<Pn, 256, 0, stream>>>(partb, meanb, wsum, out + OUT_WSUM);
}